// Round 10
// baseline (264.833 us; speedup 1.0000x reference)
//
#include <hip/hip_runtime.h>
#include <hip/hip_bf16.h>
#include <cstddef>

// ---------------------------------------------------------------------------
// 3-layer MPNN, N=50000, E=800000, D=128, OUT=32.
// R22 = R21 (verified @248us) + cross-node 2-deep gather pipeline.
// R21 counters: VGPR 64, fused_layer 45us, VALUBusy 43%, occ 30% -- SGB
// clustered loads within a node but the pipeline drains between nodes.
// Fix: software-pipeline across the 4 nodes (ISSUE(0),ISSUE(1),CONSUME(0),
// ISSUE(2),CONSUME(1),ISSUE(3),CONSUME(2),CONSUME(3)) with static dual
// register buffers (rule #20: compile-time indexed), SGB(VMEM_READ,8/4) per
// issue batch, launch_bounds(256,2) for VGPR headroom (2 nodes' load data
// = 64 VGPR live). Compiler owns all waitcnts (counted vmcnt from deps) --
// zero correctness exposure, pure reorder.
// Accounting: rest ~114us = ~42us harness 256MiB ws-fill (uncontrollable)
// + ~25us setup/bin/place + gaps. fused_layer (3x45) is the target.
// Base: R17/R21 datapath. csr entries preloaded in lanes 0-31 + shfl
// broadcast; clamp-to-last + w=0 padding; deg>32 rare scalar tail.
// Phase 2 (MFMA, W-in-regs, XOR-swizzled Gt/Ht), bin/place/setup = R21.
// CSR entry: (src:u16 | w:bf16<<16).
// ---------------------------------------------------------------------------

typedef __attribute__((ext_vector_type(8))) short short8;
typedef __attribute__((ext_vector_type(4))) float f32x4;
typedef unsigned short ushort_t;
typedef unsigned int uint_t;
typedef __attribute__((ext_vector_type(4))) uint_t u32x4;

#define BSH 8               // bucket shift: 256 nodes per bucket
#define BSZ 256             // nodes per bucket
#define CAPB 6144           // staged entries per bucket (mean 4096, >30 sigma)
#define TSTRIDE 16          // tails counter stride in ints (64B line each)
#define EPB 2048            // edges per bin block

__device__ inline ushort_t f2bf(float f) {  // round-to-nearest-even
    uint_t u = __float_as_uint(f);
    uint_t r = u + 0x7FFFu + ((u >> 16) & 1u);
    return (ushort_t)(r >> 16);
}
__device__ inline float bf_lo(uint_t u) { return __uint_as_float(u << 16); }
__device__ inline float bf_hi(uint_t u) { return __uint_as_float(u & 0xFFFF0000u); }
__device__ inline uint_t packbf(float a, float b) {
    return (uint_t)f2bf(a) | ((uint_t)f2bf(b) << 16);
}

// fast tanh: 1 - 2/(exp2(2*log2e*x)+1); saturates correctly at +-inf.
__device__ inline float fast_tanh(float x) {
    float e = __builtin_amdgcn_exp2f(x * 2.8853900817779268f);
    return 1.f - 2.f * __builtin_amdgcn_rcpf(e + 1.f);
}

// flag=1 -> int32 [2][E]; flag=0 -> int64 [2][E] (vectorized low-word read)
__device__ inline int get_dst(const int* __restrict__ ei, int e, int E, int f) {
    if (f) return ei[E + e];
    return ((const int2*)ei)[(size_t)E + e].x;
}
__device__ inline int get_src(const int* __restrict__ ei, int e, int E, int f) {
    if (f) return ei[e];
    return ((const int2*)ei)[e].x;
}

// ---------------------------------------------------------------------------
// Fused setup: zero tails+cursor | detect idx layout | swizzled bf16 weights
// | x -> bf16.
// ---------------------------------------------------------------------------
struct SetupArgs {
    const float* Wm0; const float* Wu0;
    const float* Wm1; const float* Wu1;
    const float* Wm2; const float* Wu2;
    const float* Wout;
    const float* x; const int* ei;
    ushort_t* wswz;    // 3 * 32768
    ushort_t* woswz;   // 4096
    ushort_t* xb;      // N*128
    int* tails;        // NB*TSTRIDE + cursor (zeroed together)
    int* flag;
    int N, E, TI;
    int ZT, WB, XB;
};
__global__ __launch_bounds__(256) void setup_kernel(SetupArgs a) {
    int bx = blockIdx.x, t = threadIdx.x;
    if (bx < a.ZT) {
        int i = bx * 256 + t;
        if (i < a.TI) a.tails[i] = 0;
        return;
    }
    bx -= a.ZT;
    if (bx == 0) {
        __shared__ int any;
        if (t == 0) any = 0;
        __syncthreads();
        int n = a.E < 2048 ? a.E : 2048;
        for (int i = t; i < n; i += 256)
            if (a.ei[2 * i + 1] != 0) any = 1;
        __syncthreads();
        if (t == 0) a.flag[0] = any;
        return;
    }
    bx -= 1;
    if (bx < a.WB) {
        int i = bx * 256 + t;
        if (i < 3 * 32768) {
            int l = i >> 15, r2 = i & 32767;
            int ct = r2 >> 12, ks = (r2 >> 9) & 7, lane = (r2 >> 3) & 63, j = r2 & 7;
            int col = ct * 16 + (lane & 15);
            int k = ks * 32 + (lane >> 4) * 8 + j;
            const float* Wm = l == 0 ? a.Wm0 : (l == 1 ? a.Wm1 : a.Wm2);
            const float* Wu = l == 0 ? a.Wu0 : (l == 1 ? a.Wu1 : a.Wu2);
            float v = k < 128 ? Wm[col * 128 + k] : Wu[col * 128 + (k - 128)];
            a.wswz[(size_t)l * 32768 + r2] = f2bf(v);
        } else if (i < 3 * 32768 + 4096) {
            int r2 = i - 3 * 32768;
            int ct = r2 >> 11, ks = (r2 >> 9) & 3, lane = (r2 >> 3) & 63, j = r2 & 7;
            int col = ct * 16 + (lane & 15);
            int k = ks * 32 + (lane >> 4) * 8 + j;
            a.woswz[r2] = f2bf(a.Wout[col * 128 + k]);
        }
        return;
    }
    bx -= a.WB;
    {
        int j = bx * 256 + t;
        if (j < a.N * 32) {
            float4 v = *(const float4*)(a.x + (size_t)j * 4);
            uint2 o;
            o.x = packbf(v.x, v.y);
            o.y = packbf(v.z, v.w);
            *(uint2*)(a.xb + (size_t)j * 4) = o;
        }
    }
}

// ---------------------------------------------------------------------------
// Phase A: LDS multi-split binning + counting-sort -> coalesced scatter.
// ---------------------------------------------------------------------------
__global__ __launch_bounds__(256) void bin_kernel(
    const int* __restrict__ ei, const float* __restrict__ ew,
    const int* __restrict__ flag, int* __restrict__ tails,
    uint2* __restrict__ staged, int E, int NB) {
    __shared__ uint2 ent[EPB];           // 16 KB
    __shared__ uint2 srt[EPB];           // 16 KB
    __shared__ int cnt[256], cur[256], exc[256], runbase[256];
    const int tid = threadIdx.x;
    const int e0 = blockIdx.x * EPB;
    const int nE = (E - e0) < EPB ? (E - e0) : EPB;
    const int f = flag[0];
    cnt[tid] = 0;
    cur[tid] = 0;
    __syncthreads();
    for (int i = tid; i < nE; i += 256) {
        int e = e0 + i;
        int s = get_src(ei, e, E, f);
        int d = get_dst(ei, e, E, f);
        uint2 v;
        v.x = (uint_t)s | ((uint_t)f2bf(ew[e]) << 16);
        v.y = (uint_t)d;
        ent[i] = v;
        atomicAdd(&cnt[d >> BSH], 1);    // LDS atomic
    }
    __syncthreads();
    exc[tid] = cnt[tid];
    __syncthreads();
    for (int o = 1; o < 256; o <<= 1) {
        int v = tid >= o ? exc[tid - o] : 0;
        __syncthreads();
        exc[tid] += v;
        __syncthreads();
    }
    exc[tid] -= cnt[tid];
    if (tid < NB) {
        int c = cnt[tid];
        runbase[tid] = c ? atomicAdd(&tails[tid * TSTRIDE], c) : 0;
    }
    __syncthreads();
    for (int i = tid; i < nE; i += 256) {
        uint2 v = ent[i];
        int b = (int)(v.y >> BSH);
        int lp = atomicAdd(&cur[b], 1);  // LDS atomic
        srt[exc[b] + lp] = v;
    }
    __syncthreads();
    for (int i = tid; i < nE; i += 256) {
        uint2 v = srt[i];
        int b = (int)(v.y >> BSH);
        int gp = runbase[b] + (i - exc[b]);
        if (gp < CAPB) {
            uint2 o;
            o.x = v.x;
            o.y = (uint_t)(v.y & (BSZ - 1));
            staged[(size_t)b * CAPB + gp] = o;
        }
    }
}

// ---------------------------------------------------------------------------
// Phase B: one block per bucket -> contiguous CSR region + rowdeg{beg,end}.
// ---------------------------------------------------------------------------
__global__ __launch_bounds__(256) void place_kernel(
    const uint2* __restrict__ staged, const int* __restrict__ tails,
    int* __restrict__ cursor, uint_t* __restrict__ csr,
    int2* __restrict__ rowdeg, int N) {
    __shared__ int cnt[256], cur[256], excl[256], sm[256];
    __shared__ int baseSh;
    __shared__ uint_t outb[CAPB];        // 24 KB
    const int b = blockIdx.x, tid = threadIdx.x;
    const int node0 = b << BSH;
    int tot = tails[b * TSTRIDE];
    tot = tot < CAPB ? tot : CAPB;
    cnt[tid] = 0;
    __syncthreads();
    const uint2* sp = staged + ((size_t)b * CAPB);
    for (int i = tid; i < tot; i += 256) atomicAdd(&cnt[sp[i].y], 1);
    __syncthreads();
    int c0 = cnt[tid];
    sm[tid] = c0;
    __syncthreads();
    for (int o = 1; o < 256; o <<= 1) {
        int v = tid >= o ? sm[tid - o] : 0;
        __syncthreads();
        sm[tid] += v;
        __syncthreads();
    }
    if (tid == 255) baseSh = atomicAdd(cursor, sm[255]);
    excl[tid] = sm[tid] - c0;
    cur[tid] = 0;
    __syncthreads();
    const int base = baseSh;
    for (int i = tid; i < tot; i += 256) {
        uint2 e = sp[i];
        int pos = excl[e.y] + atomicAdd(&cur[e.y], 1);
        outb[pos] = e.x;
    }
    __syncthreads();
    for (int i = tid; i < tot; i += 256) csr[base + i] = outb[i];
    if (node0 + tid < N) {
        int2 be;
        be.x = base + excl[tid];
        be.y = base + excl[tid] + c0;
        rowdeg[node0 + tid] = be;
    }
}

// ---------------------------------------------------------------------------
// Fused layer: block(256)=4 waves owns 16 rows.
// Phase 1 (R22): 2-node-deep software pipeline. Per node: csr entries from
// lanes 0-31 (preloaded) via shfl; 8 (deg>16) or 4 row loads into a static
// dual buffer; SGB(VMEM_READ) clusters each issue batch; consume overlaps
// the next node's issue. clamp + w=0 padding; deg>32 rare scalar tail.
// Phase 2: wave wv computes all 16 rows x cols [32*wv,32*wv+32), W in regs,
// A from XOR-swizzled LDS Gt/Ht. WITH_OUT: fold output GEMM via LDS h3.
// ---------------------------------------------------------------------------
#define ISSUE(I, PW, V)                                                       \
    do {                                                                      \
        _Pragma("unroll")                                                     \
        for (int b = 0; b < 8; ++b)                                           \
            PW[b] = __shfl(cent[I], (b * 4 + sl) & 31, 64);                   \
        if (degs[I] > 16) {                                                   \
            _Pragma("unroll")                                                 \
            for (int b = 0; b < 8; ++b)                                       \
                V[b] = *(const u32x4*)(h + (size_t)(PW[b] & 0xFFFFu) * 128 +  \
                                       fl * 8);                               \
            __builtin_amdgcn_sched_group_barrier(0x020, 8, 0);                \
        } else {                                                              \
            _Pragma("unroll")                                                 \
            for (int b = 0; b < 4; ++b)                                       \
                V[b] = *(const u32x4*)(h + (size_t)(PW[b] & 0xFFFFu) * 128 +  \
                                       fl * 8);                               \
            __builtin_amdgcn_sched_group_barrier(0x020, 4, 0);                \
        }                                                                     \
    } while (0)

#define CONSB(I, PW, V, B)                                                    \
    do {                                                                      \
        float w_ = ((B * 4 + sl) < degs[I]) ? bf_hi(PW[B]) : 0.f;             \
        sacc[I][0] += w_ * bf_lo(V[B][0]); sacc[I][1] += w_ * bf_hi(V[B][0]); \
        sacc[I][2] += w_ * bf_lo(V[B][1]); sacc[I][3] += w_ * bf_hi(V[B][1]); \
        sacc[I][4] += w_ * bf_lo(V[B][2]); sacc[I][5] += w_ * bf_hi(V[B][2]); \
        sacc[I][6] += w_ * bf_lo(V[B][3]); sacc[I][7] += w_ * bf_hi(V[B][3]); \
    } while (0)

#define CONSUME(I, PW, V)                                                     \
    do {                                                                      \
        CONSB(I, PW, V, 0); CONSB(I, PW, V, 1);                               \
        CONSB(I, PW, V, 2); CONSB(I, PW, V, 3);                               \
        if (degs[I] > 16) {                                                   \
            CONSB(I, PW, V, 4); CONSB(I, PW, V, 5);                           \
            CONSB(I, PW, V, 6); CONSB(I, PW, V, 7);                           \
        }                                                                     \
        if (degs[I] > 32) {                                                   \
            for (int j = begs[I] + 32 + sl; j < begs[I] + degs[I]; j += 4) {  \
                uint_t p = csr[j];                                            \
                float w = bf_hi(p);                                           \
                u32x4 vv = *(const u32x4*)(h + (size_t)(p & 0xFFFFu) * 128 +  \
                                           fl * 8);                           \
                sacc[I][0] += w * bf_lo(vv[0]); sacc[I][1] += w * bf_hi(vv[0]);\
                sacc[I][2] += w * bf_lo(vv[1]); sacc[I][3] += w * bf_hi(vv[1]);\
                sacc[I][4] += w * bf_lo(vv[2]); sacc[I][5] += w * bf_hi(vv[2]);\
                sacc[I][6] += w * bf_lo(vv[3]); sacc[I][7] += w * bf_hi(vv[3]);\
            }                                                                 \
        }                                                                     \
    } while (0)

template <int WITH_OUT>
__global__ __launch_bounds__(256, 2) void fused_layer(
    const uint_t* __restrict__ csr, const int2* __restrict__ rowdeg,
    const ushort_t* __restrict__ h, const ushort_t* __restrict__ Wswz,
    const float* __restrict__ bias, ushort_t* __restrict__ Hout,
    const ushort_t* __restrict__ Woswz, const float* __restrict__ bout,
    float* __restrict__ Cout, int N) {
    __shared__ ushort_t Gt[16 * 128];    // 4 KB, swizzled
    __shared__ ushort_t Ht[16 * 128];    // 4 KB, swizzled
    const int tid = threadIdx.x;
    const int lane = tid & 63;
    const int wv = tid >> 6;
    const int R0 = blockIdx.x * 16;
    const int sl = lane >> 4, fl = lane & 15;

    // -- T14 issue-early: H-tile load with pre-swizzled source ------------
    const int pp = tid * 16;                  // LDS byte pos (256*16B = 4KB)
    const int srow = pp >> 8;                 // local row 0..15
    const int sx = (pp & 255) ^ ((srow & 7) << 4);
    uint4 hst = *(const uint4*)(h + (size_t)(R0 + srow) * 128 + (sx >> 1));

    // -- per-node metadata + first-32 csr entries (lanes 0-31, clamped) ---
    int begs[4], degs[4];
    uint_t cent[4];
#pragma unroll
    for (int i = 0; i < 4; ++i) {
        int nd = R0 + wv * 4 + i;
        int bg = 0, dg = 0;
        if (nd < N) { int2 be = rowdeg[nd]; bg = be.x; dg = be.y - be.x; }
        begs[i] = bg; degs[i] = dg;
        cent[i] = 0;
        if (dg > 0) {
            int idx = lane & 31;
            idx = idx < dg ? idx : dg - 1;
            cent[i] = csr[bg + idx];
        }
    }

    float sacc[4][8];
#pragma unroll
    for (int i = 0; i < 4; ++i)
#pragma unroll
        for (int r = 0; r < 8; ++r) sacc[i][r] = 0.f;

    // -- phase 1: 2-node-deep pipelined gather ----------------------------
    {
        uint_t pwA[8], pwB[8];
        u32x4 vA[8], vB[8];
        ISSUE(0, pwA, vA);
        ISSUE(1, pwB, vB);
        CONSUME(0, pwA, vA);
        ISSUE(2, pwA, vA);
        CONSUME(1, pwB, vB);
        ISSUE(3, pwB, vB);
        CONSUME(2, pwA, vA);
        CONSUME(3, pwB, vB);
    }

    // -- reduce over 4 slots, pack, write swizzled Gt rows ----------------
#pragma unroll
    for (int i = 0; i < 4; ++i) {
#pragma unroll
        for (int r = 0; r < 8; ++r) {
            sacc[i][r] += __shfl_xor(sacc[i][r], 16, 64);
            sacc[i][r] += __shfl_xor(sacc[i][r], 32, 64);
        }
        if (sl == 0) {
            uint4 o;
            o.x = packbf(sacc[i][0], sacc[i][1]);
            o.y = packbf(sacc[i][2], sacc[i][3]);
            o.z = packbf(sacc[i][4], sacc[i][5]);
            o.w = packbf(sacc[i][6], sacc[i][7]);
            const int lr = wv * 4 + i;
            *(uint4*)(Gt + lr * 128 + ((fl * 8) ^ ((lr & 7) << 3))) = o;
        }
    }
    // -- write-late H tile ------------------------------------------------
    *(uint4*)((char*)Ht + pp) = hst;
    __syncthreads();

    // -- phase 2: MFMA. wave wv: all 16 rows, cols [32*wv, 32*wv+32) ------
    const int m = lane & 15, kg = lane >> 4;
    const int lsw = (m & 7) << 3;
    const int colL = lane & 15, rq = lane >> 4;

    short8 b0f[8], b1f[8];
#pragma unroll
    for (int ksp = 0; ksp < 8; ++ksp) {
        b0f[ksp] = *(const short8*)(Wswz + (((2 * wv) * 8 + ksp) * 64 + lane) * 8);
        b1f[ksp] = *(const short8*)(Wswz + (((2 * wv + 1) * 8 + ksp) * 64 + lane) * 8);
    }
    const float bv0 = bias[(2 * wv) * 16 + colL];
    const float bv1 = bias[(2 * wv + 1) * 16 + colL];

    f32x4 acc0 = (f32x4){0.f, 0.f, 0.f, 0.f};
    f32x4 acc1 = (f32x4){0.f, 0.f, 0.f, 0.f};
#pragma unroll
    for (int ksp = 0; ksp < 8; ++ksp) {
        const ushort_t* tp = (ksp < 4) ? Gt : Ht;
        short8 av = *(const short8*)(tp + m * 128 + (((ksp & 3) * 32 + kg * 8) ^ lsw));
        acc0 = __builtin_amdgcn_mfma_f32_16x16x32_bf16(av, b0f[ksp], acc0, 0, 0, 0);
        acc1 = __builtin_amdgcn_mfma_f32_16x16x32_bf16(av, b1f[ksp], acc1, 0, 0, 0);
    }
    float v0[4], v1[4];
#pragma unroll
    for (int reg = 0; reg < 4; ++reg) {
        v0[reg] = fast_tanh(acc0[reg] + bv0);
        v1[reg] = fast_tanh(acc1[reg] + bv1);
    }

    if (WITH_OUT == 0) {
#pragma unroll
        for (int reg = 0; reg < 4; ++reg) {
            int gr = R0 + rq * 4 + reg;
            if (gr < N) {
                Hout[(size_t)gr * 128 + (2 * wv) * 16 + colL] = f2bf(v0[reg]);
                Hout[(size_t)gr * 128 + (2 * wv + 1) * 16 + colL] = f2bf(v1[reg]);
            }
        }
    } else {
        // h3 -> Gt (swizzled), then out = h3 @ Woswz + bout
        __syncthreads();   // all A-reads of Gt done before overwrite
#pragma unroll
        for (int reg = 0; reg < 4; ++reg) {
            int lr3 = rq * 4 + reg;
            int sw3 = (lr3 & 7) << 3;
            Gt[lr3 * 128 + (((2 * wv) * 16 + colL) ^ sw3)] = f2bf(v0[reg]);
            Gt[lr3 * 128 + (((2 * wv + 1) * 16 + colL) ^ sw3)] = f2bf(v1[reg]);
        }
        __syncthreads();
        if (wv < 2) {
            const int oc = wv;               // col tile 0..1
            const int osw = (m & 7) << 3;
            short8 ob[4];
#pragma unroll
            for (int ks = 0; ks < 4; ++ks)
                ob[ks] = *(const short8*)(Woswz + ((oc * 4 + ks) * 64 + lane) * 8);
            f32x4 oacc = (f32x4){0.f, 0.f, 0.f, 0.f};
#pragma unroll
            for (int ks = 0; ks < 4; ++ks) {
                short8 av = *(const short8*)(Gt + m * 128 + ((ks * 32 + kg * 8) ^ osw));
                oacc = __builtin_amdgcn_mfma_f32_16x16x32_bf16(av, ob[ks], oacc, 0, 0, 0);
            }
            const float obv = bout[oc * 16 + colL];
#pragma unroll
            for (int reg = 0; reg < 4; ++reg) {
                int gr = R0 + rq * 4 + reg;
                if (gr < N) Cout[(size_t)gr * 32 + oc * 16 + colL] = oacc[reg] + obv;
            }
        }
    }
}

extern "C" void kernel_launch(void* const* d_in, const int* in_sizes, int n_in,
                              void* d_out, int out_size, void* d_ws, size_t ws_size,
                              hipStream_t stream) {
    const float* x   = (const float*)d_in[0];
    const int* ei    = (const int*)d_in[1];
    const float* ew  = (const float*)d_in[2];
    const float* Wm[3] = {(const float*)d_in[3], (const float*)d_in[6], (const float*)d_in[9]};
    const float* Wu[3] = {(const float*)d_in[4], (const float*)d_in[7], (const float*)d_in[10]};
    const float* bu[3] = {(const float*)d_in[5], (const float*)d_in[8], (const float*)d_in[11]};
    const float* Wout = (const float*)d_in[12];
    const float* bout = (const float*)d_in[13];
    float* out = (float*)d_out;

    const int N = in_sizes[0] / 128;
    const int E = in_sizes[2];
    const size_t NPAD = 50048;
    const int NB = (N + BSZ - 1) / BSZ;  // 196 buckets
    const int TI = NB * TSTRIDE + 16;    // tails + cursor (zeroed together)

    ushort_t* xb    = (ushort_t*)d_ws;              // [NPAD,128] bf16
    ushort_t* hA    = xb + NPAD * 128;
    ushort_t* hB    = hA + NPAD * 128;
    ushort_t* gbuf  = hB + NPAD * 128;              // unused (kept for layout)
    ushort_t* wswz  = gbuf + NPAD * 128;            // 3*32768 bf16
    ushort_t* woswz = wswz + 3 * 32768;             // 4096 bf16
    int* flag       = (int*)(woswz + 4096);
    int* tails      = flag + 1;
    int* cursor     = tails + NB * TSTRIDE;         // inside zeroed TI range
    int* endp       = tails + TI;
    int2* rowdeg    = (int2*)(((uintptr_t)endp + 7) & ~(uintptr_t)7);
    uint2* staged   = (uint2*)(rowdeg + N + 8);
    uint_t* csr     = (uint_t*)(staged + (size_t)NB * CAPB);
    (void)ws_size;

    const int ZT = (TI + 255) / 256;
    const int WB = (3 * 32768 + 4096 + 255) / 256;  // 400
    const int XB = (N * 32 + 255) / 256;            // 6250
    const int gB = (E + EPB - 1) / EPB;             // 391
    const int gF = (N + 15) / 16;                   // 3125

    SetupArgs sa;
    sa.Wm0 = Wm[0]; sa.Wu0 = Wu[0];
    sa.Wm1 = Wm[1]; sa.Wu1 = Wu[1];
    sa.Wm2 = Wm[2]; sa.Wu2 = Wu[2];
    sa.Wout = Wout; sa.x = x; sa.ei = ei;
    sa.wswz = wswz; sa.woswz = woswz; sa.xb = xb;
    sa.tails = tails; sa.flag = flag;
    sa.N = N; sa.E = E; sa.TI = TI;
    sa.ZT = ZT; sa.WB = WB; sa.XB = XB;
    setup_kernel<<<ZT + 1 + WB + XB, 256, 0, stream>>>(sa);

    bin_kernel<<<gB, 256, 0, stream>>>(ei, ew, flag, tails, staged, E, NB);
    place_kernel<<<NB, 256, 0, stream>>>(staged, tails, cursor, csr, rowdeg, N);

    fused_layer<0><<<gF, 256, 0, stream>>>(csr, rowdeg, xb, wswz, bu[0], hA,
                                           nullptr, nullptr, nullptr, N);
    fused_layer<0><<<gF, 256, 0, stream>>>(csr, rowdeg, hA, wswz + 32768, bu[1], hB,
                                           nullptr, nullptr, nullptr, N);
    fused_layer<1><<<gF, 256, 0, stream>>>(csr, rowdeg, hB, wswz + 2 * 32768, bu[2],
                                           nullptr, woswz, bout, out, N);
}

// Round 11
// 240.539 us; speedup vs baseline: 1.1010x; 1.1010x over previous
//
#include <hip/hip_runtime.h>
#include <hip/hip_bf16.h>
#include <cstddef>

// ---------------------------------------------------------------------------
// 3-layer MPNN, N=50000, E=800000, D=128, OUT=32.
// R23 = R21 (verified @248us) + branchless 8-deep load issue.
// R22 post-mortem: cross-node pipeline did NOT deepen (VGPR 68, compiler
// re-serialized) and launch_bounds(256,2) cost occupancy -> 264us. Reverted.
// R21's residual: deg<=16 nodes (56% of Poisson-16) issue only 4 loads ->
// 4-deep MLP on the majority path. Fix: issue ALL 8 row loads per node
// (edge indices already clamp to deg-1, so loads 5-8 for low-deg nodes hit
// the same row = L2 hits, ~no extra HBM traffic); consume hi half only when
// deg>16 (no extra VALU). Uniform 8-deep pipeline, one less branch.
// Everything else identical to R21: csr entries preloaded in lanes 0-31 +
// shfl broadcast; SGB(VMEM_READ,8) clusters the issue; clamp + w=0 padding;
// deg>32 rare scalar tail; phase 2 MFMA W-in-regs + XOR-swizzled Gt/Ht;
// bin/place/setup unchanged.  CSR entry: (src:u16 | w:bf16<<16).
// ---------------------------------------------------------------------------

typedef __attribute__((ext_vector_type(8))) short short8;
typedef __attribute__((ext_vector_type(4))) float f32x4;
typedef unsigned short ushort_t;
typedef unsigned int uint_t;
typedef __attribute__((ext_vector_type(4))) uint_t u32x4;

#define BSH 8               // bucket shift: 256 nodes per bucket
#define BSZ 256             // nodes per bucket
#define CAPB 6144           // staged entries per bucket (mean 4096, >30 sigma)
#define TSTRIDE 16          // tails counter stride in ints (64B line each)
#define EPB 2048            // edges per bin block

__device__ inline ushort_t f2bf(float f) {  // round-to-nearest-even
    uint_t u = __float_as_uint(f);
    uint_t r = u + 0x7FFFu + ((u >> 16) & 1u);
    return (ushort_t)(r >> 16);
}
__device__ inline float bf_lo(uint_t u) { return __uint_as_float(u << 16); }
__device__ inline float bf_hi(uint_t u) { return __uint_as_float(u & 0xFFFF0000u); }
__device__ inline uint_t packbf(float a, float b) {
    return (uint_t)f2bf(a) | ((uint_t)f2bf(b) << 16);
}

// fast tanh: 1 - 2/(exp2(2*log2e*x)+1); saturates correctly at +-inf.
__device__ inline float fast_tanh(float x) {
    float e = __builtin_amdgcn_exp2f(x * 2.8853900817779268f);
    return 1.f - 2.f * __builtin_amdgcn_rcpf(e + 1.f);
}

// flag=1 -> int32 [2][E]; flag=0 -> int64 [2][E] (vectorized low-word read)
__device__ inline int get_dst(const int* __restrict__ ei, int e, int E, int f) {
    if (f) return ei[E + e];
    return ((const int2*)ei)[(size_t)E + e].x;
}
__device__ inline int get_src(const int* __restrict__ ei, int e, int E, int f) {
    if (f) return ei[e];
    return ((const int2*)ei)[e].x;
}

// ---------------------------------------------------------------------------
// Fused setup: zero tails+cursor | detect idx layout | swizzled bf16 weights
// | x -> bf16.
// ---------------------------------------------------------------------------
struct SetupArgs {
    const float* Wm0; const float* Wu0;
    const float* Wm1; const float* Wu1;
    const float* Wm2; const float* Wu2;
    const float* Wout;
    const float* x; const int* ei;
    ushort_t* wswz;    // 3 * 32768
    ushort_t* woswz;   // 4096
    ushort_t* xb;      // N*128
    int* tails;        // NB*TSTRIDE + cursor (zeroed together)
    int* flag;
    int N, E, TI;
    int ZT, WB, XB;
};
__global__ __launch_bounds__(256) void setup_kernel(SetupArgs a) {
    int bx = blockIdx.x, t = threadIdx.x;
    if (bx < a.ZT) {
        int i = bx * 256 + t;
        if (i < a.TI) a.tails[i] = 0;
        return;
    }
    bx -= a.ZT;
    if (bx == 0) {
        __shared__ int any;
        if (t == 0) any = 0;
        __syncthreads();
        int n = a.E < 2048 ? a.E : 2048;
        for (int i = t; i < n; i += 256)
            if (a.ei[2 * i + 1] != 0) any = 1;
        __syncthreads();
        if (t == 0) a.flag[0] = any;
        return;
    }
    bx -= 1;
    if (bx < a.WB) {
        int i = bx * 256 + t;
        if (i < 3 * 32768) {
            int l = i >> 15, r2 = i & 32767;
            int ct = r2 >> 12, ks = (r2 >> 9) & 7, lane = (r2 >> 3) & 63, j = r2 & 7;
            int col = ct * 16 + (lane & 15);
            int k = ks * 32 + (lane >> 4) * 8 + j;
            const float* Wm = l == 0 ? a.Wm0 : (l == 1 ? a.Wm1 : a.Wm2);
            const float* Wu = l == 0 ? a.Wu0 : (l == 1 ? a.Wu1 : a.Wu2);
            float v = k < 128 ? Wm[col * 128 + k] : Wu[col * 128 + (k - 128)];
            a.wswz[(size_t)l * 32768 + r2] = f2bf(v);
        } else if (i < 3 * 32768 + 4096) {
            int r2 = i - 3 * 32768;
            int ct = r2 >> 11, ks = (r2 >> 9) & 3, lane = (r2 >> 3) & 63, j = r2 & 7;
            int col = ct * 16 + (lane & 15);
            int k = ks * 32 + (lane >> 4) * 8 + j;
            a.woswz[r2] = f2bf(a.Wout[col * 128 + k]);
        }
        return;
    }
    bx -= a.WB;
    {
        int j = bx * 256 + t;
        if (j < a.N * 32) {
            float4 v = *(const float4*)(a.x + (size_t)j * 4);
            uint2 o;
            o.x = packbf(v.x, v.y);
            o.y = packbf(v.z, v.w);
            *(uint2*)(a.xb + (size_t)j * 4) = o;
        }
    }
}

// ---------------------------------------------------------------------------
// Phase A: LDS multi-split binning + counting-sort -> coalesced scatter.
// ---------------------------------------------------------------------------
__global__ __launch_bounds__(256) void bin_kernel(
    const int* __restrict__ ei, const float* __restrict__ ew,
    const int* __restrict__ flag, int* __restrict__ tails,
    uint2* __restrict__ staged, int E, int NB) {
    __shared__ uint2 ent[EPB];           // 16 KB
    __shared__ uint2 srt[EPB];           // 16 KB
    __shared__ int cnt[256], cur[256], exc[256], runbase[256];
    const int tid = threadIdx.x;
    const int e0 = blockIdx.x * EPB;
    const int nE = (E - e0) < EPB ? (E - e0) : EPB;
    const int f = flag[0];
    cnt[tid] = 0;
    cur[tid] = 0;
    __syncthreads();
    for (int i = tid; i < nE; i += 256) {
        int e = e0 + i;
        int s = get_src(ei, e, E, f);
        int d = get_dst(ei, e, E, f);
        uint2 v;
        v.x = (uint_t)s | ((uint_t)f2bf(ew[e]) << 16);
        v.y = (uint_t)d;
        ent[i] = v;
        atomicAdd(&cnt[d >> BSH], 1);    // LDS atomic
    }
    __syncthreads();
    exc[tid] = cnt[tid];
    __syncthreads();
    for (int o = 1; o < 256; o <<= 1) {
        int v = tid >= o ? exc[tid - o] : 0;
        __syncthreads();
        exc[tid] += v;
        __syncthreads();
    }
    exc[tid] -= cnt[tid];
    if (tid < NB) {
        int c = cnt[tid];
        runbase[tid] = c ? atomicAdd(&tails[tid * TSTRIDE], c) : 0;
    }
    __syncthreads();
    for (int i = tid; i < nE; i += 256) {
        uint2 v = ent[i];
        int b = (int)(v.y >> BSH);
        int lp = atomicAdd(&cur[b], 1);  // LDS atomic
        srt[exc[b] + lp] = v;
    }
    __syncthreads();
    for (int i = tid; i < nE; i += 256) {
        uint2 v = srt[i];
        int b = (int)(v.y >> BSH);
        int gp = runbase[b] + (i - exc[b]);
        if (gp < CAPB) {
            uint2 o;
            o.x = v.x;
            o.y = (uint_t)(v.y & (BSZ - 1));
            staged[(size_t)b * CAPB + gp] = o;
        }
    }
}

// ---------------------------------------------------------------------------
// Phase B: one block per bucket -> contiguous CSR region + rowdeg{beg,end}.
// ---------------------------------------------------------------------------
__global__ __launch_bounds__(256) void place_kernel(
    const uint2* __restrict__ staged, const int* __restrict__ tails,
    int* __restrict__ cursor, uint_t* __restrict__ csr,
    int2* __restrict__ rowdeg, int N) {
    __shared__ int cnt[256], cur[256], excl[256], sm[256];
    __shared__ int baseSh;
    __shared__ uint_t outb[CAPB];        // 24 KB
    const int b = blockIdx.x, tid = threadIdx.x;
    const int node0 = b << BSH;
    int tot = tails[b * TSTRIDE];
    tot = tot < CAPB ? tot : CAPB;
    cnt[tid] = 0;
    __syncthreads();
    const uint2* sp = staged + ((size_t)b * CAPB);
    for (int i = tid; i < tot; i += 256) atomicAdd(&cnt[sp[i].y], 1);
    __syncthreads();
    int c0 = cnt[tid];
    sm[tid] = c0;
    __syncthreads();
    for (int o = 1; o < 256; o <<= 1) {
        int v = tid >= o ? sm[tid - o] : 0;
        __syncthreads();
        sm[tid] += v;
        __syncthreads();
    }
    if (tid == 255) baseSh = atomicAdd(cursor, sm[255]);
    excl[tid] = sm[tid] - c0;
    cur[tid] = 0;
    __syncthreads();
    const int base = baseSh;
    for (int i = tid; i < tot; i += 256) {
        uint2 e = sp[i];
        int pos = excl[e.y] + atomicAdd(&cur[e.y], 1);
        outb[pos] = e.x;
    }
    __syncthreads();
    for (int i = tid; i < tot; i += 256) csr[base + i] = outb[i];
    if (node0 + tid < N) {
        int2 be;
        be.x = base + excl[tid];
        be.y = base + excl[tid] + c0;
        rowdeg[node0 + tid] = be;
    }
}

// ---------------------------------------------------------------------------
// Fused layer: block(256)=4 waves owns 16 rows.
// Phase 1 (R23): per wave 4 nodes; csr entries preloaded in lanes 0-31 and
// shfl-broadcast; ALWAYS 8 row loads (clamped -> L2 hits for low-deg),
// clustered via sched_group_barrier(VMEM_READ,8); consume hi half only if
// deg>16 (wave-uniform); clamp + w=0 padding; deg>32 rare scalar tail.
// Phase 2: wave wv computes all 16 rows x cols [32*wv,32*wv+32), W in regs,
// A from XOR-swizzled LDS Gt/Ht. WITH_OUT: fold output GEMM via LDS h3.
// ---------------------------------------------------------------------------
template <int WITH_OUT>
__global__ __launch_bounds__(256, 4) void fused_layer(
    const uint_t* __restrict__ csr, const int2* __restrict__ rowdeg,
    const ushort_t* __restrict__ h, const ushort_t* __restrict__ Wswz,
    const float* __restrict__ bias, ushort_t* __restrict__ Hout,
    const ushort_t* __restrict__ Woswz, const float* __restrict__ bout,
    float* __restrict__ Cout, int N) {
    __shared__ ushort_t Gt[16 * 128];    // 4 KB, swizzled
    __shared__ ushort_t Ht[16 * 128];    // 4 KB, swizzled
    const int tid = threadIdx.x;
    const int lane = tid & 63;
    const int wv = tid >> 6;
    const int R0 = blockIdx.x * 16;
    const int sl = lane >> 4, fl = lane & 15;

    // -- T14 issue-early: H-tile load with pre-swizzled source ------------
    const int pp = tid * 16;                  // LDS byte pos (256*16B = 4KB)
    const int srow = pp >> 8;                 // local row 0..15
    const int sx = (pp & 255) ^ ((srow & 7) << 4);
    uint4 hst = *(const uint4*)(h + (size_t)(R0 + srow) * 128 + (sx >> 1));

    // -- per-node metadata + first-32 csr entries (lanes 0-31, clamped) ---
    int begs[4], degs[4];
    uint_t cent[4];
#pragma unroll
    for (int i = 0; i < 4; ++i) {
        int nd = R0 + wv * 4 + i;
        int bg = 0, dg = 0;
        if (nd < N) { int2 be = rowdeg[nd]; bg = be.x; dg = be.y - be.x; }
        begs[i] = bg; degs[i] = dg;
        cent[i] = 0;
        if (dg > 0) {
            int idx = lane & 31;
            idx = idx < dg ? idx : dg - 1;
            cent[i] = csr[bg + idx];
        }
    }

    float sacc[4][8];
#pragma unroll
    for (int i = 0; i < 4; ++i)
#pragma unroll
        for (int r = 0; r < 8; ++r) sacc[i][r] = 0.f;

    // -- phase 1: gather, 4 nodes; uniform 8-deep load issue ---------------
#pragma unroll
    for (int i = 0; i < 4; ++i) {
        uint_t pw[8];
        u32x4 v[8];
#pragma unroll
        for (int b = 0; b < 8; ++b)
            pw[b] = __shfl(cent[i], (b * 4 + sl) & 31, 64);
#pragma unroll
        for (int b = 0; b < 8; ++b)
            v[b] = *(const u32x4*)(h + (size_t)(pw[b] & 0xFFFFu) * 128 + fl * 8);
        __builtin_amdgcn_sched_group_barrier(0x020, 8, 0);   // 8 VMEM reads first
#pragma unroll
        for (int b = 0; b < 4; ++b) {
            float w = ((b * 4 + sl) < degs[i]) ? bf_hi(pw[b]) : 0.f;
            sacc[i][0] += w * bf_lo(v[b][0]); sacc[i][1] += w * bf_hi(v[b][0]);
            sacc[i][2] += w * bf_lo(v[b][1]); sacc[i][3] += w * bf_hi(v[b][1]);
            sacc[i][4] += w * bf_lo(v[b][2]); sacc[i][5] += w * bf_hi(v[b][2]);
            sacc[i][6] += w * bf_lo(v[b][3]); sacc[i][7] += w * bf_hi(v[b][3]);
        }
        if (degs[i] > 16) {              // wave-uniform: consume hi half
#pragma unroll
            for (int b = 4; b < 8; ++b) {
                float w = ((b * 4 + sl) < degs[i]) ? bf_hi(pw[b]) : 0.f;
                sacc[i][0] += w * bf_lo(v[b][0]); sacc[i][1] += w * bf_hi(v[b][0]);
                sacc[i][2] += w * bf_lo(v[b][1]); sacc[i][3] += w * bf_hi(v[b][1]);
                sacc[i][4] += w * bf_lo(v[b][2]); sacc[i][5] += w * bf_hi(v[b][2]);
                sacc[i][6] += w * bf_lo(v[b][3]); sacc[i][7] += w * bf_hi(v[b][3]);
            }
        }
        if (degs[i] > 32) {              // rare tail (~1e-4 of nodes)
            for (int j = begs[i] + 32 + sl; j < begs[i] + degs[i]; j += 4) {
                uint_t p = csr[j];
                float w = bf_hi(p);
                u32x4 vv = *(const u32x4*)(h + (size_t)(p & 0xFFFFu) * 128 + fl * 8);
                sacc[i][0] += w * bf_lo(vv[0]); sacc[i][1] += w * bf_hi(vv[0]);
                sacc[i][2] += w * bf_lo(vv[1]); sacc[i][3] += w * bf_hi(vv[1]);
                sacc[i][4] += w * bf_lo(vv[2]); sacc[i][5] += w * bf_hi(vv[2]);
                sacc[i][6] += w * bf_lo(vv[3]); sacc[i][7] += w * bf_hi(vv[3]);
            }
        }
    }

    // -- reduce over 4 slots, pack, write swizzled Gt rows ----------------
#pragma unroll
    for (int i = 0; i < 4; ++i) {
#pragma unroll
        for (int r = 0; r < 8; ++r) {
            sacc[i][r] += __shfl_xor(sacc[i][r], 16, 64);
            sacc[i][r] += __shfl_xor(sacc[i][r], 32, 64);
        }
        if (sl == 0) {
            uint4 o;
            o.x = packbf(sacc[i][0], sacc[i][1]);
            o.y = packbf(sacc[i][2], sacc[i][3]);
            o.z = packbf(sacc[i][4], sacc[i][5]);
            o.w = packbf(sacc[i][6], sacc[i][7]);
            const int lr = wv * 4 + i;
            *(uint4*)(Gt + lr * 128 + ((fl * 8) ^ ((lr & 7) << 3))) = o;
        }
    }
    // -- write-late H tile ------------------------------------------------
    *(uint4*)((char*)Ht + pp) = hst;
    __syncthreads();

    // -- phase 2: MFMA. wave wv: all 16 rows, cols [32*wv, 32*wv+32) ------
    const int m = lane & 15, kg = lane >> 4;
    const int lsw = (m & 7) << 3;
    const int colL = lane & 15, rq = lane >> 4;

    short8 b0f[8], b1f[8];
#pragma unroll
    for (int ksp = 0; ksp < 8; ++ksp) {
        b0f[ksp] = *(const short8*)(Wswz + (((2 * wv) * 8 + ksp) * 64 + lane) * 8);
        b1f[ksp] = *(const short8*)(Wswz + (((2 * wv + 1) * 8 + ksp) * 64 + lane) * 8);
    }
    const float bv0 = bias[(2 * wv) * 16 + colL];
    const float bv1 = bias[(2 * wv + 1) * 16 + colL];

    f32x4 acc0 = (f32x4){0.f, 0.f, 0.f, 0.f};
    f32x4 acc1 = (f32x4){0.f, 0.f, 0.f, 0.f};
#pragma unroll
    for (int ksp = 0; ksp < 8; ++ksp) {
        const ushort_t* tp = (ksp < 4) ? Gt : Ht;
        short8 av = *(const short8*)(tp + m * 128 + (((ksp & 3) * 32 + kg * 8) ^ lsw));
        acc0 = __builtin_amdgcn_mfma_f32_16x16x32_bf16(av, b0f[ksp], acc0, 0, 0, 0);
        acc1 = __builtin_amdgcn_mfma_f32_16x16x32_bf16(av, b1f[ksp], acc1, 0, 0, 0);
    }
    float v0[4], v1[4];
#pragma unroll
    for (int reg = 0; reg < 4; ++reg) {
        v0[reg] = fast_tanh(acc0[reg] + bv0);
        v1[reg] = fast_tanh(acc1[reg] + bv1);
    }

    if (WITH_OUT == 0) {
#pragma unroll
        for (int reg = 0; reg < 4; ++reg) {
            int gr = R0 + rq * 4 + reg;
            if (gr < N) {
                Hout[(size_t)gr * 128 + (2 * wv) * 16 + colL] = f2bf(v0[reg]);
                Hout[(size_t)gr * 128 + (2 * wv + 1) * 16 + colL] = f2bf(v1[reg]);
            }
        }
    } else {
        // h3 -> Gt (swizzled), then out = h3 @ Woswz + bout
        __syncthreads();   // all A-reads of Gt done before overwrite
#pragma unroll
        for (int reg = 0; reg < 4; ++reg) {
            int lr3 = rq * 4 + reg;
            int sw3 = (lr3 & 7) << 3;
            Gt[lr3 * 128 + (((2 * wv) * 16 + colL) ^ sw3)] = f2bf(v0[reg]);
            Gt[lr3 * 128 + (((2 * wv + 1) * 16 + colL) ^ sw3)] = f2bf(v1[reg]);
        }
        __syncthreads();
        if (wv < 2) {
            const int oc = wv;               // col tile 0..1
            const int osw = (m & 7) << 3;
            short8 ob[4];
#pragma unroll
            for (int ks = 0; ks < 4; ++ks)
                ob[ks] = *(const short8*)(Woswz + ((oc * 4 + ks) * 64 + lane) * 8);
            f32x4 oacc = (f32x4){0.f, 0.f, 0.f, 0.f};
#pragma unroll
            for (int ks = 0; ks < 4; ++ks) {
                short8 av = *(const short8*)(Gt + m * 128 + ((ks * 32 + kg * 8) ^ osw));
                oacc = __builtin_amdgcn_mfma_f32_16x16x32_bf16(av, ob[ks], oacc, 0, 0, 0);
            }
            const float obv = bout[oc * 16 + colL];
#pragma unroll
            for (int reg = 0; reg < 4; ++reg) {
                int gr = R0 + rq * 4 + reg;
                if (gr < N) Cout[(size_t)gr * 32 + oc * 16 + colL] = oacc[reg] + obv;
            }
        }
    }
}

extern "C" void kernel_launch(void* const* d_in, const int* in_sizes, int n_in,
                              void* d_out, int out_size, void* d_ws, size_t ws_size,
                              hipStream_t stream) {
    const float* x   = (const float*)d_in[0];
    const int* ei    = (const int*)d_in[1];
    const float* ew  = (const float*)d_in[2];
    const float* Wm[3] = {(const float*)d_in[3], (const float*)d_in[6], (const float*)d_in[9]};
    const float* Wu[3] = {(const float*)d_in[4], (const float*)d_in[7], (const float*)d_in[10]};
    const float* bu[3] = {(const float*)d_in[5], (const float*)d_in[8], (const float*)d_in[11]};
    const float* Wout = (const float*)d_in[12];
    const float* bout = (const float*)d_in[13];
    float* out = (float*)d_out;

    const int N = in_sizes[0] / 128;
    const int E = in_sizes[2];
    const size_t NPAD = 50048;
    const int NB = (N + BSZ - 1) / BSZ;  // 196 buckets
    const int TI = NB * TSTRIDE + 16;    // tails + cursor (zeroed together)

    ushort_t* xb    = (ushort_t*)d_ws;              // [NPAD,128] bf16
    ushort_t* hA    = xb + NPAD * 128;
    ushort_t* hB    = hA + NPAD * 128;
    ushort_t* gbuf  = hB + NPAD * 128;              // unused (kept for layout)
    ushort_t* wswz  = gbuf + NPAD * 128;            // 3*32768 bf16
    ushort_t* woswz = wswz + 3 * 32768;             // 4096 bf16
    int* flag       = (int*)(woswz + 4096);
    int* tails      = flag + 1;
    int* cursor     = tails + NB * TSTRIDE;         // inside zeroed TI range
    int* endp       = tails + TI;
    int2* rowdeg    = (int2*)(((uintptr_t)endp + 7) & ~(uintptr_t)7);
    uint2* staged   = (uint2*)(rowdeg + N + 8);
    uint_t* csr     = (uint_t*)(staged + (size_t)NB * CAPB);
    (void)ws_size;

    const int ZT = (TI + 255) / 256;
    const int WB = (3 * 32768 + 4096 + 255) / 256;  // 400
    const int XB = (N * 32 + 255) / 256;            // 6250
    const int gB = (E + EPB - 1) / EPB;             // 391
    const int gF = (N + 15) / 16;                   // 3125

    SetupArgs sa;
    sa.Wm0 = Wm[0]; sa.Wu0 = Wu[0];
    sa.Wm1 = Wm[1]; sa.Wu1 = Wu[1];
    sa.Wm2 = Wm[2]; sa.Wu2 = Wu[2];
    sa.Wout = Wout; sa.x = x; sa.ei = ei;
    sa.wswz = wswz; sa.woswz = woswz; sa.xb = xb;
    sa.tails = tails; sa.flag = flag;
    sa.N = N; sa.E = E; sa.TI = TI;
    sa.ZT = ZT; sa.WB = WB; sa.XB = XB;
    setup_kernel<<<ZT + 1 + WB + XB, 256, 0, stream>>>(sa);

    bin_kernel<<<gB, 256, 0, stream>>>(ei, ew, flag, tails, staged, E, NB);
    place_kernel<<<NB, 256, 0, stream>>>(staged, tails, cursor, csr, rowdeg, N);

    fused_layer<0><<<gF, 256, 0, stream>>>(csr, rowdeg, xb, wswz, bu[0], hA,
                                           nullptr, nullptr, nullptr, N);
    fused_layer<0><<<gF, 256, 0, stream>>>(csr, rowdeg, hA, wswz + 32768, bu[1], hB,
                                           nullptr, nullptr, nullptr, N);
    fused_layer<1><<<gF, 256, 0, stream>>>(csr, rowdeg, hB, wswz + 2 * 32768, bu[2],
                                           nullptr, woswz, bout, out, N);
}

// Round 12
// 237.882 us; speedup vs baseline: 1.1133x; 1.0112x over previous
//
#include <hip/hip_runtime.h>
#include <hip/hip_bf16.h>
#include <cstddef>

// ---------------------------------------------------------------------------
// 3-layer MPNN, N=50000, E=800000, D=128, OUT=32.
// R24 = R23 (verified @240.5us) + phase-1 live-state reduction.
// R23's uniform-8 issue keeps v[8](32 VGPR) + sacc[4][8](32) + pw(8) live
// together (~96 VGPR -> ~5 waves/SIMD). Fix: reduce+pack+Gt-store INSIDE the
// per-node loop so only sacc[8] is loop-carried (saves 24 VGPR, identical
// semantics -- Gt is read only after the barrier). Target: VGPR <= ~72 ->
// 7-8 waves/SIMD, TLP hides the per-node issue->wait->consume drains that
// ILP could not (R22 lesson: compiler won't pipeline cross-node).
// Everything else identical to R23: csr entries preloaded lanes 0-31 + shfl
// broadcast; ALWAYS 8 row loads (clamped; low-deg extras are L2 hits);
// SGB(VMEM_READ,8); consume hi half only if deg>16; deg>32 scalar tail;
// phase 2 MFMA W-in-regs + XOR-swizzled Gt/Ht; bin/place/setup unchanged.
// CSR entry: (src:u16 | w:bf16<<16).
// ---------------------------------------------------------------------------

typedef __attribute__((ext_vector_type(8))) short short8;
typedef __attribute__((ext_vector_type(4))) float f32x4;
typedef unsigned short ushort_t;
typedef unsigned int uint_t;
typedef __attribute__((ext_vector_type(4))) uint_t u32x4;

#define BSH 8               // bucket shift: 256 nodes per bucket
#define BSZ 256             // nodes per bucket
#define CAPB 6144           // staged entries per bucket (mean 4096, >30 sigma)
#define TSTRIDE 16          // tails counter stride in ints (64B line each)
#define EPB 2048            // edges per bin block

__device__ inline ushort_t f2bf(float f) {  // round-to-nearest-even
    uint_t u = __float_as_uint(f);
    uint_t r = u + 0x7FFFu + ((u >> 16) & 1u);
    return (ushort_t)(r >> 16);
}
__device__ inline float bf_lo(uint_t u) { return __uint_as_float(u << 16); }
__device__ inline float bf_hi(uint_t u) { return __uint_as_float(u & 0xFFFF0000u); }
__device__ inline uint_t packbf(float a, float b) {
    return (uint_t)f2bf(a) | ((uint_t)f2bf(b) << 16);
}

// fast tanh: 1 - 2/(exp2(2*log2e*x)+1); saturates correctly at +-inf.
__device__ inline float fast_tanh(float x) {
    float e = __builtin_amdgcn_exp2f(x * 2.8853900817779268f);
    return 1.f - 2.f * __builtin_amdgcn_rcpf(e + 1.f);
}

// flag=1 -> int32 [2][E]; flag=0 -> int64 [2][E] (vectorized low-word read)
__device__ inline int get_dst(const int* __restrict__ ei, int e, int E, int f) {
    if (f) return ei[E + e];
    return ((const int2*)ei)[(size_t)E + e].x;
}
__device__ inline int get_src(const int* __restrict__ ei, int e, int E, int f) {
    if (f) return ei[e];
    return ((const int2*)ei)[e].x;
}

// ---------------------------------------------------------------------------
// Fused setup: zero tails+cursor | detect idx layout | swizzled bf16 weights
// | x -> bf16.
// ---------------------------------------------------------------------------
struct SetupArgs {
    const float* Wm0; const float* Wu0;
    const float* Wm1; const float* Wu1;
    const float* Wm2; const float* Wu2;
    const float* Wout;
    const float* x; const int* ei;
    ushort_t* wswz;    // 3 * 32768
    ushort_t* woswz;   // 4096
    ushort_t* xb;      // N*128
    int* tails;        // NB*TSTRIDE + cursor (zeroed together)
    int* flag;
    int N, E, TI;
    int ZT, WB, XB;
};
__global__ __launch_bounds__(256) void setup_kernel(SetupArgs a) {
    int bx = blockIdx.x, t = threadIdx.x;
    if (bx < a.ZT) {
        int i = bx * 256 + t;
        if (i < a.TI) a.tails[i] = 0;
        return;
    }
    bx -= a.ZT;
    if (bx == 0) {
        __shared__ int any;
        if (t == 0) any = 0;
        __syncthreads();
        int n = a.E < 2048 ? a.E : 2048;
        for (int i = t; i < n; i += 256)
            if (a.ei[2 * i + 1] != 0) any = 1;
        __syncthreads();
        if (t == 0) a.flag[0] = any;
        return;
    }
    bx -= 1;
    if (bx < a.WB) {
        int i = bx * 256 + t;
        if (i < 3 * 32768) {
            int l = i >> 15, r2 = i & 32767;
            int ct = r2 >> 12, ks = (r2 >> 9) & 7, lane = (r2 >> 3) & 63, j = r2 & 7;
            int col = ct * 16 + (lane & 15);
            int k = ks * 32 + (lane >> 4) * 8 + j;
            const float* Wm = l == 0 ? a.Wm0 : (l == 1 ? a.Wm1 : a.Wm2);
            const float* Wu = l == 0 ? a.Wu0 : (l == 1 ? a.Wu1 : a.Wu2);
            float v = k < 128 ? Wm[col * 128 + k] : Wu[col * 128 + (k - 128)];
            a.wswz[(size_t)l * 32768 + r2] = f2bf(v);
        } else if (i < 3 * 32768 + 4096) {
            int r2 = i - 3 * 32768;
            int ct = r2 >> 11, ks = (r2 >> 9) & 3, lane = (r2 >> 3) & 63, j = r2 & 7;
            int col = ct * 16 + (lane & 15);
            int k = ks * 32 + (lane >> 4) * 8 + j;
            a.woswz[r2] = f2bf(a.Wout[col * 128 + k]);
        }
        return;
    }
    bx -= a.WB;
    {
        int j = bx * 256 + t;
        if (j < a.N * 32) {
            float4 v = *(const float4*)(a.x + (size_t)j * 4);
            uint2 o;
            o.x = packbf(v.x, v.y);
            o.y = packbf(v.z, v.w);
            *(uint2*)(a.xb + (size_t)j * 4) = o;
        }
    }
}

// ---------------------------------------------------------------------------
// Phase A: LDS multi-split binning + counting-sort -> coalesced scatter.
// ---------------------------------------------------------------------------
__global__ __launch_bounds__(256) void bin_kernel(
    const int* __restrict__ ei, const float* __restrict__ ew,
    const int* __restrict__ flag, int* __restrict__ tails,
    uint2* __restrict__ staged, int E, int NB) {
    __shared__ uint2 ent[EPB];           // 16 KB
    __shared__ uint2 srt[EPB];           // 16 KB
    __shared__ int cnt[256], cur[256], exc[256], runbase[256];
    const int tid = threadIdx.x;
    const int e0 = blockIdx.x * EPB;
    const int nE = (E - e0) < EPB ? (E - e0) : EPB;
    const int f = flag[0];
    cnt[tid] = 0;
    cur[tid] = 0;
    __syncthreads();
    for (int i = tid; i < nE; i += 256) {
        int e = e0 + i;
        int s = get_src(ei, e, E, f);
        int d = get_dst(ei, e, E, f);
        uint2 v;
        v.x = (uint_t)s | ((uint_t)f2bf(ew[e]) << 16);
        v.y = (uint_t)d;
        ent[i] = v;
        atomicAdd(&cnt[d >> BSH], 1);    // LDS atomic
    }
    __syncthreads();
    exc[tid] = cnt[tid];
    __syncthreads();
    for (int o = 1; o < 256; o <<= 1) {
        int v = tid >= o ? exc[tid - o] : 0;
        __syncthreads();
        exc[tid] += v;
        __syncthreads();
    }
    exc[tid] -= cnt[tid];
    if (tid < NB) {
        int c = cnt[tid];
        runbase[tid] = c ? atomicAdd(&tails[tid * TSTRIDE], c) : 0;
    }
    __syncthreads();
    for (int i = tid; i < nE; i += 256) {
        uint2 v = ent[i];
        int b = (int)(v.y >> BSH);
        int lp = atomicAdd(&cur[b], 1);  // LDS atomic
        srt[exc[b] + lp] = v;
    }
    __syncthreads();
    for (int i = tid; i < nE; i += 256) {
        uint2 v = srt[i];
        int b = (int)(v.y >> BSH);
        int gp = runbase[b] + (i - exc[b]);
        if (gp < CAPB) {
            uint2 o;
            o.x = v.x;
            o.y = (uint_t)(v.y & (BSZ - 1));
            staged[(size_t)b * CAPB + gp] = o;
        }
    }
}

// ---------------------------------------------------------------------------
// Phase B: one block per bucket -> contiguous CSR region + rowdeg{beg,end}.
// ---------------------------------------------------------------------------
__global__ __launch_bounds__(256) void place_kernel(
    const uint2* __restrict__ staged, const int* __restrict__ tails,
    int* __restrict__ cursor, uint_t* __restrict__ csr,
    int2* __restrict__ rowdeg, int N) {
    __shared__ int cnt[256], cur[256], excl[256], sm[256];
    __shared__ int baseSh;
    __shared__ uint_t outb[CAPB];        // 24 KB
    const int b = blockIdx.x, tid = threadIdx.x;
    const int node0 = b << BSH;
    int tot = tails[b * TSTRIDE];
    tot = tot < CAPB ? tot : CAPB;
    cnt[tid] = 0;
    __syncthreads();
    const uint2* sp = staged + ((size_t)b * CAPB);
    for (int i = tid; i < tot; i += 256) atomicAdd(&cnt[sp[i].y], 1);
    __syncthreads();
    int c0 = cnt[tid];
    sm[tid] = c0;
    __syncthreads();
    for (int o = 1; o < 256; o <<= 1) {
        int v = tid >= o ? sm[tid - o] : 0;
        __syncthreads();
        sm[tid] += v;
        __syncthreads();
    }
    if (tid == 255) baseSh = atomicAdd(cursor, sm[255]);
    excl[tid] = sm[tid] - c0;
    cur[tid] = 0;
    __syncthreads();
    const int base = baseSh;
    for (int i = tid; i < tot; i += 256) {
        uint2 e = sp[i];
        int pos = excl[e.y] + atomicAdd(&cur[e.y], 1);
        outb[pos] = e.x;
    }
    __syncthreads();
    for (int i = tid; i < tot; i += 256) csr[base + i] = outb[i];
    if (node0 + tid < N) {
        int2 be;
        be.x = base + excl[tid];
        be.y = base + excl[tid] + c0;
        rowdeg[node0 + tid] = be;
    }
}

// ---------------------------------------------------------------------------
// Fused layer: block(256)=4 waves owns 16 rows.
// Phase 1 (R24): per wave 4 nodes processed fully one at a time (gather ->
// reduce -> Gt store inside the loop; only sacc[8] loop-carried). Uniform
// 8-deep load issue (clamped), SGB(VMEM_READ,8); hi-half consume if deg>16;
// deg>32 rare scalar tail.
// Phase 2: wave wv computes all 16 rows x cols [32*wv,32*wv+32), W in regs,
// A from XOR-swizzled LDS Gt/Ht. WITH_OUT: fold output GEMM via LDS h3.
// ---------------------------------------------------------------------------
template <int WITH_OUT>
__global__ __launch_bounds__(256, 4) void fused_layer(
    const uint_t* __restrict__ csr, const int2* __restrict__ rowdeg,
    const ushort_t* __restrict__ h, const ushort_t* __restrict__ Wswz,
    const float* __restrict__ bias, ushort_t* __restrict__ Hout,
    const ushort_t* __restrict__ Woswz, const float* __restrict__ bout,
    float* __restrict__ Cout, int N) {
    __shared__ ushort_t Gt[16 * 128];    // 4 KB, swizzled
    __shared__ ushort_t Ht[16 * 128];    // 4 KB, swizzled
    const int tid = threadIdx.x;
    const int lane = tid & 63;
    const int wv = tid >> 6;
    const int R0 = blockIdx.x * 16;
    const int sl = lane >> 4, fl = lane & 15;

    // -- T14 issue-early: H-tile load with pre-swizzled source ------------
    const int pp = tid * 16;                  // LDS byte pos (256*16B = 4KB)
    const int srow = pp >> 8;                 // local row 0..15
    const int sx = (pp & 255) ^ ((srow & 7) << 4);
    uint4 hst = *(const uint4*)(h + (size_t)(R0 + srow) * 128 + (sx >> 1));

    // -- per-node metadata + first-32 csr entries (lanes 0-31, clamped) ---
    int begs[4], degs[4];
    uint_t cent[4];
#pragma unroll
    for (int i = 0; i < 4; ++i) {
        int nd = R0 + wv * 4 + i;
        int bg = 0, dg = 0;
        if (nd < N) { int2 be = rowdeg[nd]; bg = be.x; dg = be.y - be.x; }
        begs[i] = bg; degs[i] = dg;
        cent[i] = 0;
        if (dg > 0) {
            int idx = lane & 31;
            idx = idx < dg ? idx : dg - 1;
            cent[i] = csr[bg + idx];
        }
    }

    // -- phase 1: gather, 4 nodes, fully processed one at a time -----------
#pragma unroll
    for (int i = 0; i < 4; ++i) {
        float sacc[8];
#pragma unroll
        for (int r = 0; r < 8; ++r) sacc[r] = 0.f;
        uint_t pw[8];
        u32x4 v[8];
#pragma unroll
        for (int b = 0; b < 8; ++b)
            pw[b] = __shfl(cent[i], (b * 4 + sl) & 31, 64);
#pragma unroll
        for (int b = 0; b < 8; ++b)
            v[b] = *(const u32x4*)(h + (size_t)(pw[b] & 0xFFFFu) * 128 + fl * 8);
        __builtin_amdgcn_sched_group_barrier(0x020, 8, 0);   // 8 VMEM reads first
#pragma unroll
        for (int b = 0; b < 4; ++b) {
            float w = ((b * 4 + sl) < degs[i]) ? bf_hi(pw[b]) : 0.f;
            sacc[0] += w * bf_lo(v[b][0]); sacc[1] += w * bf_hi(v[b][0]);
            sacc[2] += w * bf_lo(v[b][1]); sacc[3] += w * bf_hi(v[b][1]);
            sacc[4] += w * bf_lo(v[b][2]); sacc[5] += w * bf_hi(v[b][2]);
            sacc[6] += w * bf_lo(v[b][3]); sacc[7] += w * bf_hi(v[b][3]);
        }
        if (degs[i] > 16) {              // wave-uniform: consume hi half
#pragma unroll
            for (int b = 4; b < 8; ++b) {
                float w = ((b * 4 + sl) < degs[i]) ? bf_hi(pw[b]) : 0.f;
                sacc[0] += w * bf_lo(v[b][0]); sacc[1] += w * bf_hi(v[b][0]);
                sacc[2] += w * bf_lo(v[b][1]); sacc[3] += w * bf_hi(v[b][1]);
                sacc[4] += w * bf_lo(v[b][2]); sacc[5] += w * bf_hi(v[b][2]);
                sacc[6] += w * bf_lo(v[b][3]); sacc[7] += w * bf_hi(v[b][3]);
            }
        }
        if (degs[i] > 32) {              // rare tail (~1e-4 of nodes)
            for (int j = begs[i] + 32 + sl; j < begs[i] + degs[i]; j += 4) {
                uint_t p = csr[j];
                float w = bf_hi(p);
                u32x4 vv = *(const u32x4*)(h + (size_t)(p & 0xFFFFu) * 128 + fl * 8);
                sacc[0] += w * bf_lo(vv[0]); sacc[1] += w * bf_hi(vv[0]);
                sacc[2] += w * bf_lo(vv[1]); sacc[3] += w * bf_hi(vv[1]);
                sacc[4] += w * bf_lo(vv[2]); sacc[5] += w * bf_hi(vv[2]);
                sacc[6] += w * bf_lo(vv[3]); sacc[7] += w * bf_hi(vv[3]);
            }
        }
        // reduce over 4 slots, pack, write swizzled Gt row (immediately)
#pragma unroll
        for (int r = 0; r < 8; ++r) {
            sacc[r] += __shfl_xor(sacc[r], 16, 64);
            sacc[r] += __shfl_xor(sacc[r], 32, 64);
        }
        if (sl == 0) {
            uint4 o;
            o.x = packbf(sacc[0], sacc[1]);
            o.y = packbf(sacc[2], sacc[3]);
            o.z = packbf(sacc[4], sacc[5]);
            o.w = packbf(sacc[6], sacc[7]);
            const int lr = wv * 4 + i;
            *(uint4*)(Gt + lr * 128 + ((fl * 8) ^ ((lr & 7) << 3))) = o;
        }
    }
    // -- write-late H tile ------------------------------------------------
    *(uint4*)((char*)Ht + pp) = hst;
    __syncthreads();

    // -- phase 2: MFMA. wave wv: all 16 rows, cols [32*wv, 32*wv+32) ------
    const int m = lane & 15, kg = lane >> 4;
    const int lsw = (m & 7) << 3;
    const int colL = lane & 15, rq = lane >> 4;

    short8 b0f[8], b1f[8];
#pragma unroll
    for (int ksp = 0; ksp < 8; ++ksp) {
        b0f[ksp] = *(const short8*)(Wswz + (((2 * wv) * 8 + ksp) * 64 + lane) * 8);
        b1f[ksp] = *(const short8*)(Wswz + (((2 * wv + 1) * 8 + ksp) * 64 + lane) * 8);
    }
    const float bv0 = bias[(2 * wv) * 16 + colL];
    const float bv1 = bias[(2 * wv + 1) * 16 + colL];

    f32x4 acc0 = (f32x4){0.f, 0.f, 0.f, 0.f};
    f32x4 acc1 = (f32x4){0.f, 0.f, 0.f, 0.f};
#pragma unroll
    for (int ksp = 0; ksp < 8; ++ksp) {
        const ushort_t* tp = (ksp < 4) ? Gt : Ht;
        short8 av = *(const short8*)(tp + m * 128 + (((ksp & 3) * 32 + kg * 8) ^ lsw));
        acc0 = __builtin_amdgcn_mfma_f32_16x16x32_bf16(av, b0f[ksp], acc0, 0, 0, 0);
        acc1 = __builtin_amdgcn_mfma_f32_16x16x32_bf16(av, b1f[ksp], acc1, 0, 0, 0);
    }
    float v0[4], v1[4];
#pragma unroll
    for (int reg = 0; reg < 4; ++reg) {
        v0[reg] = fast_tanh(acc0[reg] + bv0);
        v1[reg] = fast_tanh(acc1[reg] + bv1);
    }

    if (WITH_OUT == 0) {
#pragma unroll
        for (int reg = 0; reg < 4; ++reg) {
            int gr = R0 + rq * 4 + reg;
            if (gr < N) {
                Hout[(size_t)gr * 128 + (2 * wv) * 16 + colL] = f2bf(v0[reg]);
                Hout[(size_t)gr * 128 + (2 * wv + 1) * 16 + colL] = f2bf(v1[reg]);
            }
        }
    } else {
        // h3 -> Gt (swizzled), then out = h3 @ Woswz + bout
        __syncthreads();   // all A-reads of Gt done before overwrite
#pragma unroll
        for (int reg = 0; reg < 4; ++reg) {
            int lr3 = rq * 4 + reg;
            int sw3 = (lr3 & 7) << 3;
            Gt[lr3 * 128 + (((2 * wv) * 16 + colL) ^ sw3)] = f2bf(v0[reg]);
            Gt[lr3 * 128 + (((2 * wv + 1) * 16 + colL) ^ sw3)] = f2bf(v1[reg]);
        }
        __syncthreads();
        if (wv < 2) {
            const int oc = wv;               // col tile 0..1
            const int osw = (m & 7) << 3;
            short8 ob[4];
#pragma unroll
            for (int ks = 0; ks < 4; ++ks)
                ob[ks] = *(const short8*)(Woswz + ((oc * 4 + ks) * 64 + lane) * 8);
            f32x4 oacc = (f32x4){0.f, 0.f, 0.f, 0.f};
#pragma unroll
            for (int ks = 0; ks < 4; ++ks) {
                short8 av = *(const short8*)(Gt + m * 128 + ((ks * 32 + kg * 8) ^ osw));
                oacc = __builtin_amdgcn_mfma_f32_16x16x32_bf16(av, ob[ks], oacc, 0, 0, 0);
            }
            const float obv = bout[oc * 16 + colL];
#pragma unroll
            for (int reg = 0; reg < 4; ++reg) {
                int gr = R0 + rq * 4 + reg;
                if (gr < N) Cout[(size_t)gr * 32 + oc * 16 + colL] = oacc[reg] + obv;
            }
        }
    }
}

extern "C" void kernel_launch(void* const* d_in, const int* in_sizes, int n_in,
                              void* d_out, int out_size, void* d_ws, size_t ws_size,
                              hipStream_t stream) {
    const float* x   = (const float*)d_in[0];
    const int* ei    = (const int*)d_in[1];
    const float* ew  = (const float*)d_in[2];
    const float* Wm[3] = {(const float*)d_in[3], (const float*)d_in[6], (const float*)d_in[9]};
    const float* Wu[3] = {(const float*)d_in[4], (const float*)d_in[7], (const float*)d_in[10]};
    const float* bu[3] = {(const float*)d_in[5], (const float*)d_in[8], (const float*)d_in[11]};
    const float* Wout = (const float*)d_in[12];
    const float* bout = (const float*)d_in[13];
    float* out = (float*)d_out;

    const int N = in_sizes[0] / 128;
    const int E = in_sizes[2];
    const size_t NPAD = 50048;
    const int NB = (N + BSZ - 1) / BSZ;  // 196 buckets
    const int TI = NB * TSTRIDE + 16;    // tails + cursor (zeroed together)

    ushort_t* xb    = (ushort_t*)d_ws;              // [NPAD,128] bf16
    ushort_t* hA    = xb + NPAD * 128;
    ushort_t* hB    = hA + NPAD * 128;
    ushort_t* gbuf  = hB + NPAD * 128;              // unused (kept for layout)
    ushort_t* wswz  = gbuf + NPAD * 128;            // 3*32768 bf16
    ushort_t* woswz = wswz + 3 * 32768;             // 4096 bf16
    int* flag       = (int*)(woswz + 4096);
    int* tails      = flag + 1;
    int* cursor     = tails + NB * TSTRIDE;         // inside zeroed TI range
    int* endp       = tails + TI;
    int2* rowdeg    = (int2*)(((uintptr_t)endp + 7) & ~(uintptr_t)7);
    uint2* staged   = (uint2*)(rowdeg + N + 8);
    uint_t* csr     = (uint_t*)(staged + (size_t)NB * CAPB);
    (void)ws_size;

    const int ZT = (TI + 255) / 256;
    const int WB = (3 * 32768 + 4096 + 255) / 256;  // 400
    const int XB = (N * 32 + 255) / 256;            // 6250
    const int gB = (E + EPB - 1) / EPB;             // 391
    const int gF = (N + 15) / 16;                   // 3125

    SetupArgs sa;
    sa.Wm0 = Wm[0]; sa.Wu0 = Wu[0];
    sa.Wm1 = Wm[1]; sa.Wu1 = Wu[1];
    sa.Wm2 = Wm[2]; sa.Wu2 = Wu[2];
    sa.Wout = Wout; sa.x = x; sa.ei = ei;
    sa.wswz = wswz; sa.woswz = woswz; sa.xb = xb;
    sa.tails = tails; sa.flag = flag;
    sa.N = N; sa.E = E; sa.TI = TI;
    sa.ZT = ZT; sa.WB = WB; sa.XB = XB;
    setup_kernel<<<ZT + 1 + WB + XB, 256, 0, stream>>>(sa);

    bin_kernel<<<gB, 256, 0, stream>>>(ei, ew, flag, tails, staged, E, NB);
    place_kernel<<<NB, 256, 0, stream>>>(staged, tails, cursor, csr, rowdeg, N);

    fused_layer<0><<<gF, 256, 0, stream>>>(csr, rowdeg, xb, wswz, bu[0], hA,
                                           nullptr, nullptr, nullptr, N);
    fused_layer<0><<<gF, 256, 0, stream>>>(csr, rowdeg, hA, wswz + 32768, bu[1], hB,
                                           nullptr, nullptr, nullptr, N);
    fused_layer<1><<<gF, 256, 0, stream>>>(csr, rowdeg, hB, wswz + 2 * 32768, bu[2],
                                           nullptr, woswz, bout, out, N);
}